// Round 3
// baseline (347.084 us; speedup 1.0000x reference)
//
#include <hip/hip_runtime.h>
#include <hip/hip_bf16.h>

#define PED   512
#define HDIM  64
#define EDIM  32
#define NPAIR (PED * PED)          // 262144 rows
#define GATES 256                  // 4*H
#define WF_ELEMS (16 * 64 * 24)    // B frags: [nt][lane][kstep*8+jj], bf16
#define OS    68                   // LDS transpose-tile row stride in floats (272 B, 16B-aligned)

typedef __attribute__((ext_vector_type(8))) __bf16 bf16x8;
typedef __attribute__((ext_vector_type(4))) float  floatx4;

__device__ __forceinline__ float sigmoidf_fast(float x) {
    // single v_exp + single v_rcp (avoid the ~8-op exact-divide expansion)
    return __builtin_amdgcn_rcpf(1.0f + __expf(-x));
}
__device__ __forceinline__ float tanhf_fast(float x) {
    return fmaf(2.0f, __builtin_amdgcn_rcpf(1.0f + __expf(-2.0f * x)), -1.0f);
}

// ---- prep: weights -> bf16 MFMA B-fragment order in d_ws, bias sums ----
// Wf[(nt*64 + lane)*24 + kstep*8 + jj] = W_cat[nt*16 + (lane&15)][kstep*32 + (lane>>4)*8 + jj]
__global__ void sra_prep(const float* __restrict__ W_ih, const float* __restrict__ W_hh,
                         const float* __restrict__ b_ih, const float* __restrict__ b_hh,
                         __bf16* __restrict__ Wf, float* __restrict__ bsum)
{
    int tid = blockIdx.x * 256 + threadIdx.x;
    if (tid < WF_ELEMS) {
        int m    = tid % 24;
        int nl   = tid / 24;
        int lane = nl & 63;
        int nt   = nl >> 6;
        int n = nt * 16 + (lane & 15);
        int k = (m >> 3) * 32 + (lane >> 4) * 8 + (m & 7);
        float w = (k < EDIM) ? W_ih[n * EDIM + k] : W_hh[n * HDIM + (k - EDIM)];
        Wf[tid] = (__bf16)w;
    }
    if (tid < GATES) bsum[tid] = b_ih[tid] + b_hh[tid];
}

// ---- main: one 16-row tile per wave, 4 waves/block, 4096 blocks ----
// LDS: 4x4.25KB transpose buffers + 1KB bias = 18.4 KB/block -> 7 blocks/CU at
// __launch_bounds__(256,7) (~85% occupancy; VGPR cap 73).
__global__ __launch_bounds__(256, 7)
void sra_main(const float* __restrict__ corr,   // [P*P, 2]
              const float* __restrict__ ht,     // [P*P, 64]
              const float* __restrict__ ct,     // [P*P, 64]
              const int*   __restrict__ nei,    // [P*P]
              const float* __restrict__ W_emb,  // [32, 2]
              const float* __restrict__ b_emb,  // [32]
              const __bf16* __restrict__ Wf,    // [16*64*24] frag-order weights
              const float* __restrict__ bsumg,  // [256]
              float* __restrict__ h_out,
              float* __restrict__ c_out)
{
    __shared__ float bsum[GATES];
    __shared__ __align__(16) float OT[4][16 * OS];   // per-wave transpose scratch

    const int tid  = threadIdx.x;
    const int wave = tid >> 6;
    const int lane = tid & 63;
    const int lo   = lane & 15;
    const int qu   = lane >> 4;

    bsum[tid] = bsumg[tid];
    __syncthreads();   // only block-level barrier

    float* ot = &OT[wave][0];
    const int tile = blockIdx.x * 4 + wave;
    const int rb   = tile * 16;

    // ---- A frag 0: embedding, k in [0,32) ----
    float2 x = *(const float2*)(corr + (size_t)(rb + lo) * 2);
    bf16x8 a0;
#pragma unroll
    for (int j = 0; j < 8; ++j) {
        int e = qu * 8 + j;
        float v = fmaf(x.x, W_emb[e * 2 + 0], fmaf(x.y, W_emb[e * 2 + 1], b_emb[e]));
        a0[j] = (__bf16)fmaxf(v, 0.0f);
    }

    // ---- A frags 1,2: h row-layout loads (full lines), k in [32,96) ----
    const size_t rowoff = (size_t)(rb + lo) * HDIM + qu * 8;
    float4 h0a = *(const float4*)(ht + rowoff);
    float4 h0b = *(const float4*)(ht + rowoff + 4);
    float4 h1a = *(const float4*)(ht + rowoff + 32);
    float4 h1b = *(const float4*)(ht + rowoff + 36);
    bf16x8 a1, a2;
    a1[0] = (__bf16)h0a.x; a1[1] = (__bf16)h0a.y; a1[2] = (__bf16)h0a.z; a1[3] = (__bf16)h0a.w;
    a1[4] = (__bf16)h0b.x; a1[5] = (__bf16)h0b.y; a1[6] = (__bf16)h0b.z; a1[7] = (__bf16)h0b.w;
    a2[0] = (__bf16)h1a.x; a2[1] = (__bf16)h1a.y; a2[2] = (__bf16)h1a.z; a2[3] = (__bf16)h1a.w;
    a2[4] = (__bf16)h1b.x; a2[5] = (__bf16)h1b.y; a2[6] = (__bf16)h1b.z; a2[7] = (__bf16)h1b.w;

    // ---- GEMM: 16 rows x 256 gates, K=96; B frags streamed from global (L2-hot) ----
    floatx4 acc[16];
    const __bf16* bbase = Wf + lane * 24;
#pragma unroll
    for (int nt = 0; nt < 16; ++nt) {
        const __bf16* bp = bbase + nt * 1536;
        bf16x8 b0 = *(const bf16x8*)(bp);
        bf16x8 b1 = *(const bf16x8*)(bp + 8);
        bf16x8 b2 = *(const bf16x8*)(bp + 16);
        floatx4 c = {0.f, 0.f, 0.f, 0.f};
        c = __builtin_amdgcn_mfma_f32_16x16x32_bf16(a0, b0, c, 0, 0, 0);
        c = __builtin_amdgcn_mfma_f32_16x16x32_bf16(a1, b1, c, 0, 0, 0);
        c = __builtin_amdgcn_mfma_f32_16x16x32_bf16(a2, b2, c, 0, 0, 0);
        acc[nt] = c;
    }

    // ---- epilogue in C-layout: n = nt*16 + lo, local row rl = qu*4 + r ----
    int msk[4];
#pragma unroll
    for (int r = 0; r < 4; ++r) msk[r] = nei[rb + qu * 4 + r];

    const float* ctb = ct + (size_t)rb * HDIM;
    const float* htb = ht + (size_t)rb * HDIM;   // L1-hot: same 4KB tile as A-frags

#pragma unroll
    for (int tt = 0; tt < 4; ++tt) {
        const int k = tt * 16 + lo;
        const float bi  = bsum[k];
        const float bff = bsum[64 + k];
        const float bg  = bsum[128 + k];
        const float bo  = bsum[192 + k];
#pragma unroll
        for (int r = 0; r < 4; ++r) {
            const int rl = qu * 4 + r;
            float cold = ctb[rl * HDIM + k];     // C-layout gather, 4x64B segs/instr
            float hold = htb[rl * HDIM + k];
            float iv = sigmoidf_fast(acc[tt][r] + bi);
            float fv = sigmoidf_fast(acc[4 + tt][r] + bff);
            float gv = tanhf_fast(acc[8 + tt][r] + bg);
            float ov = sigmoidf_fast(acc[12 + tt][r] + bo);
            float cn = fv * cold + iv * gv;
            float hn = ov * tanhf_fast(cn);
            bool m = msk[r] > 0;
            ot[rl * OS + k] = m ? cn : cold;     // c result -> LDS
            acc[tt][r]      = m ? hn : hold;     // h result -> reuse acc regs
        }
    }

    // ---- c: row-major readback, 1KB contiguous stores ----
    float* hbase = h_out + (size_t)rb * HDIM;
    float* cbase = c_out + (size_t)rb * HDIM;
#pragma unroll
    for (int j = 0; j < 4; ++j) {
        int fi  = j * 64 + lane;
        int row = fi >> 4;
        int c4  = fi & 15;
        float4 vc = *(float4*)(ot + row * OS + c4 * 4);
        *(float4*)(cbase + fi * 4) = vc;
    }

    // ---- h: reuse the same LDS buffer ----
#pragma unroll
    for (int tt = 0; tt < 4; ++tt) {
        const int k = tt * 16 + lo;
#pragma unroll
        for (int r = 0; r < 4; ++r)
            ot[(qu * 4 + r) * OS + k] = acc[tt][r];
    }
#pragma unroll
    for (int j = 0; j < 4; ++j) {
        int fi  = j * 64 + lane;
        int row = fi >> 4;
        int c4  = fi & 15;
        float4 vh = *(float4*)(ot + row * OS + c4 * 4);
        *(float4*)(hbase + fi * 4) = vh;
    }
}

extern "C" void kernel_launch(void* const* d_in, const int* in_sizes, int n_in,
                              void* d_out, int out_size, void* d_ws, size_t ws_size,
                              hipStream_t stream) {
    const float* corr  = (const float*)d_in[0];
    const float* ht    = (const float*)d_in[1];
    const float* ct    = (const float*)d_in[2];
    const int*   nei   = (const int*)  d_in[3];
    const float* W_emb = (const float*)d_in[4];
    const float* b_emb = (const float*)d_in[5];
    const float* W_ih  = (const float*)d_in[6];
    const float* W_hh  = (const float*)d_in[7];
    const float* b_ih  = (const float*)d_in[8];
    const float* b_hh  = (const float*)d_in[9];

    __bf16* Wf   = (__bf16*)d_ws;                        // 49152 B
    float*  bsum = (float*)((char*)d_ws + WF_ELEMS * 2); // 1024 B

    float* hout = (float*)d_out;
    float* cout = hout + (size_t)NPAIR * HDIM;

    hipLaunchKernelGGL(sra_prep, dim3(96), dim3(256), 0, stream,
                       W_ih, W_hh, b_ih, b_hh, Wf, bsum);
    hipLaunchKernelGGL(sra_main, dim3(NPAIR / 64), dim3(256), 0, stream,
                       corr, ht, ct, nei, W_emb, b_emb, Wf, bsum, hout, cout);
}

// Round 4
// 308.334 us; speedup vs baseline: 1.1257x; 1.1257x over previous
//
#include <hip/hip_runtime.h>
#include <hip/hip_bf16.h>

#define PED   512
#define HDIM  64
#define EDIM  32
#define NPAIR (PED * PED)          // 262144 rows
#define GATES 256                  // 4*H
#define WF_ELEMS (16 * 64 * 24)    // B frags: [nt][lane][kstep*8+jj], bf16
#define OS    68                   // LDS transpose-tile row stride in floats (272 B, 16B-aligned)

typedef __attribute__((ext_vector_type(8))) __bf16 bf16x8;
typedef __attribute__((ext_vector_type(4))) float  floatx4;

__device__ __forceinline__ float sigmoidf_fast(float x) {
    return __builtin_amdgcn_rcpf(1.0f + __expf(-x));
}
__device__ __forceinline__ float tanhf_fast(float x) {
    return fmaf(2.0f, __builtin_amdgcn_rcpf(1.0f + __expf(-2.0f * x)), -1.0f);
}

// ---- prep: weights -> bf16 MFMA B-fragment order in d_ws, bias sums ----
__global__ void sra_prep(const float* __restrict__ W_ih, const float* __restrict__ W_hh,
                         const float* __restrict__ b_ih, const float* __restrict__ b_hh,
                         __bf16* __restrict__ Wf, float* __restrict__ bsum)
{
    int tid = blockIdx.x * 256 + threadIdx.x;
    if (tid < WF_ELEMS) {
        int m    = tid % 24;
        int nl   = tid / 24;
        int lane = nl & 63;
        int nt   = nl >> 6;
        int n = nt * 16 + (lane & 15);
        int k = (m >> 3) * 32 + (lane >> 4) * 8 + (m & 7);
        float w = (k < EDIM) ? W_ih[n * EDIM + k] : W_hh[n * HDIM + (k - EDIM)];
        Wf[tid] = (__bf16)w;
    }
    if (tid < GATES) bsum[tid] = b_ih[tid] + b_hh[tid];
}

// ---- main: one 16-row tile per wave; interleaved MFMA groups + epilogue slices
// keep peak live accumulators at 16 regs (vs 64 in R2/R3 -> R3 spilled at cap 73).
// LDS 18.4 KB/block; __launch_bounds__(256,6): cap 85 VGPR, 6 blocks/CU (75%).
__global__ __launch_bounds__(256, 6)
void sra_main(const float* __restrict__ corr,
              const float* __restrict__ ht,
              const float* __restrict__ ct,
              const int*   __restrict__ nei,
              const float* __restrict__ W_emb,
              const float* __restrict__ b_emb,
              const __bf16* __restrict__ Wf,
              const float* __restrict__ bsumg,
              float* __restrict__ h_out,
              float* __restrict__ c_out)
{
    __shared__ float bsum[GATES];
    __shared__ __align__(16) float OT[4][16 * OS];   // per-wave transpose scratch

    const int tid  = threadIdx.x;
    const int wave = tid >> 6;
    const int lane = tid & 63;
    const int lo   = lane & 15;
    const int qu   = lane >> 4;

    bsum[tid] = bsumg[tid];
    __syncthreads();

    float* ot = &OT[wave][0];
    const int tile = blockIdx.x * 4 + wave;
    const int rb   = tile * 16;

    // ---- A frag 0: embedding, k in [0,32) ----
    float2 x = *(const float2*)(corr + (size_t)(rb + lo) * 2);
    bf16x8 a0;
#pragma unroll
    for (int j = 0; j < 8; ++j) {
        int e = qu * 8 + j;
        float v = fmaf(x.x, W_emb[e * 2 + 0], fmaf(x.y, W_emb[e * 2 + 1], b_emb[e]));
        a0[j] = (__bf16)fmaxf(v, 0.0f);
    }

    // ---- A frags 1,2: h row-layout loads (full lines), k in [32,96) ----
    const size_t rowoff = (size_t)(rb + lo) * HDIM + qu * 8;
    float4 h0a = *(const float4*)(ht + rowoff);
    float4 h0b = *(const float4*)(ht + rowoff + 4);
    float4 h1a = *(const float4*)(ht + rowoff + 32);
    float4 h1b = *(const float4*)(ht + rowoff + 36);
    bf16x8 a1, a2;
    a1[0] = (__bf16)h0a.x; a1[1] = (__bf16)h0a.y; a1[2] = (__bf16)h0a.z; a1[3] = (__bf16)h0a.w;
    a1[4] = (__bf16)h0b.x; a1[5] = (__bf16)h0b.y; a1[6] = (__bf16)h0b.z; a1[7] = (__bf16)h0b.w;
    a2[0] = (__bf16)h1a.x; a2[1] = (__bf16)h1a.y; a2[2] = (__bf16)h1a.z; a2[3] = (__bf16)h1a.w;
    a2[4] = (__bf16)h1b.x; a2[5] = (__bf16)h1b.y; a2[6] = (__bf16)h1b.z; a2[7] = (__bf16)h1b.w;

    const __bf16* bbase = Wf + lane * 24;
    const float*  ctb   = ct + (size_t)rb * HDIM;
    const float*  htb   = ht + (size_t)rb * HDIM;   // L1/L2-hot: same tile as A-frags

    int msk[4];
#pragma unroll
    for (int r = 0; r < 4; ++r) msk[r] = nei[rb + qu * 4 + r];

    floatx4 hres[4];   // masked h results, written out after c

    // ---- interleaved: per tt, 12 MFMAs (gate tiles tt, 4+tt, 8+tt, 12+tt) + epilogue ----
#pragma unroll
    for (int tt = 0; tt < 4; ++tt) {
        const __bf16* bpi = bbase + (tt     ) * 1536;
        const __bf16* bpf = bbase + (tt +  4) * 1536;
        const __bf16* bpg = bbase + (tt +  8) * 1536;
        const __bf16* bpo = bbase + (tt + 12) * 1536;

        floatx4 zi = {0.f,0.f,0.f,0.f};
        floatx4 ai = __builtin_amdgcn_mfma_f32_16x16x32_bf16(a0, *(const bf16x8*)(bpi),      zi, 0,0,0);
        floatx4 af = __builtin_amdgcn_mfma_f32_16x16x32_bf16(a0, *(const bf16x8*)(bpf),      zi, 0,0,0);
        floatx4 ag = __builtin_amdgcn_mfma_f32_16x16x32_bf16(a0, *(const bf16x8*)(bpg),      zi, 0,0,0);
        floatx4 ao = __builtin_amdgcn_mfma_f32_16x16x32_bf16(a0, *(const bf16x8*)(bpo),      zi, 0,0,0);
        ai = __builtin_amdgcn_mfma_f32_16x16x32_bf16(a1, *(const bf16x8*)(bpi + 8),  ai, 0,0,0);
        af = __builtin_amdgcn_mfma_f32_16x16x32_bf16(a1, *(const bf16x8*)(bpf + 8),  af, 0,0,0);
        ag = __builtin_amdgcn_mfma_f32_16x16x32_bf16(a1, *(const bf16x8*)(bpg + 8),  ag, 0,0,0);
        ao = __builtin_amdgcn_mfma_f32_16x16x32_bf16(a1, *(const bf16x8*)(bpo + 8),  ao, 0,0,0);
        ai = __builtin_amdgcn_mfma_f32_16x16x32_bf16(a2, *(const bf16x8*)(bpi + 16), ai, 0,0,0);
        af = __builtin_amdgcn_mfma_f32_16x16x32_bf16(a2, *(const bf16x8*)(bpf + 16), af, 0,0,0);
        ag = __builtin_amdgcn_mfma_f32_16x16x32_bf16(a2, *(const bf16x8*)(bpg + 16), ag, 0,0,0);
        ao = __builtin_amdgcn_mfma_f32_16x16x32_bf16(a2, *(const bf16x8*)(bpo + 16), ao, 0,0,0);

        const int k = tt * 16 + lo;
        const float bi  = bsum[k];
        const float bff = bsum[64 + k];
        const float bg  = bsum[128 + k];
        const float bo  = bsum[192 + k];
#pragma unroll
        for (int r = 0; r < 4; ++r) {
            const int rl = qu * 4 + r;
            float cold = ctb[rl * HDIM + k];
            float hold = htb[rl * HDIM + k];
            float iv = sigmoidf_fast(ai[r] + bi);
            float fv = sigmoidf_fast(af[r] + bff);
            float gv = tanhf_fast(ag[r] + bg);
            float ov = sigmoidf_fast(ao[r] + bo);
            float cn = fv * cold + iv * gv;
            float hn = ov * tanhf_fast(cn);
            bool m = msk[r] > 0;
            ot[rl * OS + k] = m ? cn : cold;   // c result -> LDS transpose buffer
            hres[tt][r]     = m ? hn : hold;   // h result -> regs (16 total)
        }
    }

    // ---- c: row-major readback, 1KB contiguous stores ----
    float* hbase = h_out + (size_t)rb * HDIM;
    float* cbase = c_out + (size_t)rb * HDIM;
#pragma unroll
    for (int j = 0; j < 4; ++j) {
        int fi  = j * 64 + lane;
        int row = fi >> 4;
        int c4  = fi & 15;
        float4 vc = *(float4*)(ot + row * OS + c4 * 4);
        *(float4*)(cbase + fi * 4) = vc;
    }

    // ---- h: reuse the same LDS buffer ----
#pragma unroll
    for (int tt = 0; tt < 4; ++tt) {
        const int k = tt * 16 + lo;
#pragma unroll
        for (int r = 0; r < 4; ++r)
            ot[(qu * 4 + r) * OS + k] = hres[tt][r];
    }
#pragma unroll
    for (int j = 0; j < 4; ++j) {
        int fi  = j * 64 + lane;
        int row = fi >> 4;
        int c4  = fi & 15;
        float4 vh = *(float4*)(ot + row * OS + c4 * 4);
        *(float4*)(hbase + fi * 4) = vh;
    }
}

extern "C" void kernel_launch(void* const* d_in, const int* in_sizes, int n_in,
                              void* d_out, int out_size, void* d_ws, size_t ws_size,
                              hipStream_t stream) {
    const float* corr  = (const float*)d_in[0];
    const float* ht    = (const float*)d_in[1];
    const float* ct    = (const float*)d_in[2];
    const int*   nei   = (const int*)  d_in[3];
    const float* W_emb = (const float*)d_in[4];
    const float* b_emb = (const float*)d_in[5];
    const float* W_ih  = (const float*)d_in[6];
    const float* W_hh  = (const float*)d_in[7];
    const float* b_ih  = (const float*)d_in[8];
    const float* b_hh  = (const float*)d_in[9];

    __bf16* Wf   = (__bf16*)d_ws;                        // 49152 B
    float*  bsum = (float*)((char*)d_ws + WF_ELEMS * 2); // 1024 B

    float* hout = (float*)d_out;
    float* cout = hout + (size_t)NPAIR * HDIM;

    hipLaunchKernelGGL(sra_prep, dim3(96), dim3(256), 0, stream,
                       W_ih, W_hh, b_ih, b_hh, Wf, bsum);
    hipLaunchKernelGGL(sra_main, dim3(NPAIR / 64), dim3(256), 0, stream,
                       corr, ht, ct, nei, W_emb, b_emb, Wf, bsum, hout, cout);
}